// Round 3
// baseline (171.903 us; speedup 1.0000x reference)
//
#include <hip/hip_runtime.h>
#include <hip/hip_bf16.h>
#include <math.h>

#define B 8192
#define D 128
#define NCHUNK 16
#define CPC (B / NCHUNK)   /* 512 cols per chunk */
#define CT 64              /* cols per LDS tile */
#define NCT (CPC / CT)     /* 8 tiles per chunk */
#define BROWS 256          /* rows per block (4 waves x 64) */
#define MARGIN 1.0f

typedef short short8 __attribute__((ext_vector_type(8)));
typedef float f32x4 __attribute__((ext_vector_type(4)));

// ws layout:
//   sqn  [B] float | posE [B] uint | negE [B] uint | Xh (ushort, B*256: hi|lo bf16, swizzled)

__device__ inline ushort f2bf(float f) {
    __hip_bfloat16 h = __float2bfloat16(f);
    ushort u; __builtin_memcpy(&u, &h, 2); return u;
}
__device__ inline float bf2f(ushort u) {
    unsigned int i = ((unsigned)u) << 16; float f; __builtin_memcpy(&f, &i, 4); return f;
}
// order-preserving float<->uint encoding (uint compare == float compare)
__device__ inline unsigned fenc(float f) {
    unsigned u = __float_as_uint(f);
    return (u & 0x80000000u) ? ~u : (u | 0x80000000u);
}
__device__ inline float fdec(unsigned m) {
    unsigned u = (m & 0x80000000u) ? (m & 0x7FFFFFFFu) : ~m;
    return __uint_as_float(u);
}

__device__ inline void gload_lds16(const void* gsrc, void* ldst) {
    __builtin_amdgcn_global_load_lds(
        (const __attribute__((address_space(1))) unsigned int*)gsrc,
        (__attribute__((address_space(3))) unsigned int*)ldst,
        16, 0, 0);
}

// Fused prep: bf16 hi/lo split (swizzled), row sq-norms, min/max atomic init, out zero.
__global__ void mmcl_prep_kernel(const float* __restrict__ X,
                                 ushort* __restrict__ Xh,
                                 float* __restrict__ sqn,
                                 unsigned* __restrict__ posE,
                                 unsigned* __restrict__ negE,
                                 float* __restrict__ out) {
    const int t  = blockIdx.x * 256 + threadIdx.x;
    const int r  = t >> 4;
    const int kg = t & 15;
    const float4 v0 = *(const float4*)(X + (size_t)r * D + kg * 8);
    const float4 v1 = *(const float4*)(X + (size_t)r * D + kg * 8 + 4);
    const float xs[8] = {v0.x, v0.y, v0.z, v0.w, v1.x, v1.y, v1.z, v1.w};

    float s = 0.f;
    #pragma unroll
    for (int i = 0; i < 8; ++i) s = fmaf(xs[i], xs[i], s);
    #pragma unroll
    for (int off = 1; off < 16; off <<= 1) s += __shfl_xor(s, off);
    if (kg == 0) sqn[r] = s;

    short8 hv, lv;
    #pragma unroll
    for (int i = 0; i < 8; ++i) {
        const float x = xs[i];
        const ushort h = f2bf(x);
        hv[i] = (short)h;
        lv[i] = (short)f2bf(x - bf2f(h));
    }
    const int sw = r & 7;
    ushort* rp = Xh + (size_t)r * 256;
    *(short8*)(rp + ((kg ^ sw) << 3))        = hv;
    *(short8*)(rp + (((16 + kg) ^ sw) << 3)) = lv;

    if (t < B) { posE[t] = 0xFF800000u; negE[t] = 0x007FFFFFu; }  // enc(+INF), enc(-INF)
    if (t == 0) *out = 0.0f;
}

__global__ __launch_bounds__(256, 2) void mmcl_mfma_kernel(
    const ushort* __restrict__ Xh, const float* __restrict__ sqn,
    const int* __restrict__ lab,
    unsigned* __restrict__ posE, unsigned* __restrict__ negE)
{
    __shared__ ushort lds[2][CT * 256];   // 2 x 32KB, hi|lo per col row, swizzled
    const int tid  = threadIdx.x;
    const int wid  = tid >> 6;
    const int lane = tid & 63;
    const int lhi  = lane >> 4;
    const int llo  = lane & 15;
    const int Rblk = blockIdx.x * BROWS;
    const int R    = Rblk + wid * 64;
    const int C0   = blockIdx.y * CPC;

    // A fragments: rows R + m*16 + llo, all K=128 (hi+lo) resident in registers.
    short8 a_hi[4][4], a_lo[4][4];
    #pragma unroll
    for (int m = 0; m < 4; ++m) {
        const int row = R + m * 16 + llo;
        const int sw = row & 7;
        const ushort* rp = Xh + (size_t)row * 256;
        #pragma unroll
        for (int kf = 0; kf < 4; ++kf) {
            const int g = kf * 4 + lhi;
            a_hi[m][kf] = *(const short8*)(rp + ((g ^ sw) << 3));
            a_lo[m][kf] = *(const short8*)(rp + (((16 + g) ^ sw) << 3));
        }
    }

    int labR[4][4];
    #pragma unroll
    for (int m = 0; m < 4; ++m)
        #pragma unroll
        for (int r = 0; r < 4; ++r)
            labR[m][r] = lab[R + m * 16 + lhi * 4 + r];

    float minpos[4][4], maxneg[4][4];
    #pragma unroll
    for (int m = 0; m < 4; ++m)
        #pragma unroll
        for (int r = 0; r < 4; ++r) { minpos[m][r] = INFINITY; maxneg[m][r] = -INFINITY; }

    auto stage = [&](int buf, int t) {
        const char* g = (const char*)(Xh + (size_t)(C0 + t * CT) * 256) + wid * 8192 + lane * 16;
        char* l = (char*)&lds[buf][0] + wid * 8192;
        #pragma unroll
        for (int i = 0; i < 8; ++i)
            gload_lds16(g + i * 1024, l + i * 1024);
    };

    stage(0, 0);

    // prefetch col metadata (sq-norm + label) for tile 0
    float sqc_pf[4]; int lc_pf[4];
    #pragma unroll
    for (int n = 0; n < 4; ++n) {
        const int col = C0 + n * 16 + llo;
        sqc_pf[n] = sqn[col];
        lc_pf[n]  = lab[col];
    }

    #pragma unroll 2
    for (int t = 0; t < NCT; ++t) {
        const int cur = t & 1;
        __syncthreads();                     // drains stage(cur); all waves done reading cur^1
        if (t + 1 < NCT) stage(cur ^ 1, t + 1);

        const int colbase = C0 + t * CT;

        // consume this tile's prefetched metadata; issue next tile's immediately
        float sqc_u[4]; int lc_u[4];
        #pragma unroll
        for (int n = 0; n < 4; ++n) { sqc_u[n] = sqc_pf[n]; lc_u[n] = lc_pf[n]; }
        if (t + 1 < NCT) {
            #pragma unroll
            for (int n = 0; n < 4; ++n) {
                const int col = colbase + CT + n * 16 + llo;
                sqc_pf[n] = sqn[col];
                lc_pf[n]  = lab[col];
            }
        }

        const bool hasdiag = (colbase + CT > Rblk) && (colbase < Rblk + BROWS);

        #pragma unroll
        for (int n = 0; n < 4; ++n) {
            const int cl = n * 16 + llo;     // (global col)&7 == cl&7
            const int sw = cl & 7;
            const ushort* bp = &lds[cur][cl * 256];
            f32x4 acc[4];
            #pragma unroll
            for (int m = 0; m < 4; ++m) acc[m] = (f32x4){0.f, 0.f, 0.f, 0.f};

            __builtin_amdgcn_s_setprio(1);
            #pragma unroll
            for (int kf = 0; kf < 4; ++kf) {
                const int g = kf * 4 + lhi;
                const short8 b_hi = *(const short8*)(bp + ((g ^ sw) << 3));
                const short8 b_lo = *(const short8*)(bp + (((16 + g) ^ sw) << 3));
                #pragma unroll
                for (int m = 0; m < 4; ++m) {
                    acc[m] = __builtin_amdgcn_mfma_f32_16x16x32_bf16(a_hi[m][kf], b_hi, acc[m], 0, 0, 0);
                    acc[m] = __builtin_amdgcn_mfma_f32_16x16x32_bf16(a_hi[m][kf], b_lo, acc[m], 0, 0, 0);
                    acc[m] = __builtin_amdgcn_mfma_f32_16x16x32_bf16(a_lo[m][kf], b_hi, acc[m], 0, 0, 0);
                }
            }
            __builtin_amdgcn_s_setprio(0);

            const int col   = colbase + cl;
            const float sqc = sqc_u[n];
            const int   lc  = lc_u[n];
            if (hasdiag) {
                #pragma unroll
                for (int m = 0; m < 4; ++m) {
                    const int rowb = R + m * 16 + lhi * 4;
                    #pragma unroll
                    for (int r = 0; r < 4; ++r) {
                        const float v = fmaf(-2.0f, acc[m][r], sqc);
                        const bool same = (labR[m][r] == lc);
                        const bool diag = (rowb + r == col);
                        if (same && !diag) minpos[m][r] = fminf(minpos[m][r], v);
                        if (!same)         maxneg[m][r] = fmaxf(maxneg[m][r], v);
                    }
                }
            } else {
                #pragma unroll
                for (int m = 0; m < 4; ++m) {
                    #pragma unroll
                    for (int r = 0; r < 4; ++r) {
                        const float v = fmaf(-2.0f, acc[m][r], sqc);
                        const bool same = (labR[m][r] == lc);
                        if (same) minpos[m][r] = fminf(minpos[m][r], v);
                        else      maxneg[m][r] = fmaxf(maxneg[m][r], v);
                    }
                }
            }
        }
    }

    // reduce across the 16 llo lanes (cols), then one atomic per row
    #pragma unroll
    for (int m = 0; m < 4; ++m)
        #pragma unroll
        for (int r = 0; r < 4; ++r) {
            float mp = minpos[m][r], mn = maxneg[m][r];
            #pragma unroll
            for (int off = 1; off < 16; off <<= 1) {
                mp = fminf(mp, __shfl_xor(mp, off));
                mn = fmaxf(mn, __shfl_xor(mn, off));
            }
            if (llo == 0) {
                const int row = R + m * 16 + lhi * 4 + r;
                atomicMin(&posE[row], fenc(mp));
                atomicMax(&negE[row], fenc(mn));
            }
        }
}

__global__ void mmcl_final_kernel(const float* __restrict__ sqn,
                                  const unsigned* __restrict__ posE,
                                  const unsigned* __restrict__ negE,
                                  float* __restrict__ out)
{
    const int row = blockIdx.x * 256 + threadIdx.x;
    const float mp = fdec(posE[row]);
    const float mn = fdec(negE[row]);
    const float sq  = sqn[row];
    const float pos = isinf(mp) ? INFINITY : sqrtf(fmaxf(sq + mp, 0.f));
    const float neg = (mn == -INFINITY) ? -INFINITY : sqrtf(fmaxf(sq + mn, 0.f));
    const float term = fmaxf(pos - neg + MARGIN, 0.f);

    float s = term;
    #pragma unroll
    for (int off = 32; off; off >>= 1) s += __shfl_down(s, off);
    __shared__ float wsum[4];
    const int wave = threadIdx.x >> 6, lane = threadIdx.x & 63;
    if (lane == 0) wsum[wave] = s;
    __syncthreads();
    if (threadIdx.x == 0)
        atomicAdd(out, (wsum[0] + wsum[1] + wsum[2] + wsum[3]) * (1.0f / B));
}

extern "C" void kernel_launch(void* const* d_in, const int* in_sizes, int n_in,
                              void* d_out, int out_size, void* d_ws, size_t ws_size,
                              hipStream_t stream) {
    (void)in_sizes; (void)n_in; (void)out_size; (void)ws_size;
    const float* X   = (const float*)d_in[0];
    const int*   lab = (const int*)d_in[1];
    float* out = (float*)d_out;

    float*    sqn  = (float*)d_ws;
    unsigned* posE = (unsigned*)(sqn + B);
    unsigned* negE = posE + B;
    ushort*   Xh   = (ushort*)(negE + B);

    mmcl_prep_kernel<<<(B * 16) / 256, 256, 0, stream>>>(X, Xh, sqn, posE, negE, out);
    mmcl_mfma_kernel<<<dim3(B / BROWS, NCHUNK), 256, 0, stream>>>(Xh, sqn, lab, posE, negE);
    mmcl_final_kernel<<<B / 256, 256, 0, stream>>>(sqn, posE, negE, out);
}

// Round 4
// 154.176 us; speedup vs baseline: 1.1150x; 1.1150x over previous
//
#include <hip/hip_runtime.h>
#include <hip/hip_bf16.h>
#include <math.h>

#define B 8192
#define D 128
#define RB 128                 /* rows/cols per pair-block side */
#define NB (B / RB)            /* 64 row-blocks */
#define NPAIR (NB * (NB + 1) / 2) /* 2080 */
#define CT 32                  /* cols per LDS tile */
#define NCT (RB / CT)          /* 4 tiles */
#define NSLOT NB               /* 64 partial slots per row */
#define MARGIN 1.0f

typedef short short8 __attribute__((ext_vector_type(8)));
typedef float f32x4 __attribute__((ext_vector_type(4)));

// ws layout: sqn [B] f32 | ppos [B*NSLOT] f32 | pneg [B*NSLOT] f32 | Xh [B*256] ushort

__device__ inline ushort f2bf(float f) {
    __hip_bfloat16 h = __float2bfloat16(f);
    ushort u; __builtin_memcpy(&u, &h, 2); return u;
}
__device__ inline float bf2f(ushort u) {
    unsigned int i = ((unsigned)u) << 16; float f; __builtin_memcpy(&f, &i, 4); return f;
}

__device__ inline void gload_lds16(const void* gsrc, void* ldst) {
    __builtin_amdgcn_global_load_lds(
        (const __attribute__((address_space(1))) unsigned int*)gsrc,
        (__attribute__((address_space(3))) unsigned int*)ldst,
        16, 0, 0);
}

// Fused prep: bf16 hi/lo split (16B-granule swizzle by row&7), row sq-norms, out zero.
__global__ void mmcl_prep_kernel(const float* __restrict__ X,
                                 ushort* __restrict__ Xh,
                                 float* __restrict__ sqn,
                                 float* __restrict__ out) {
    const int t  = blockIdx.x * 256 + threadIdx.x;
    const int r  = t >> 4;
    const int kg = t & 15;
    const float4 v0 = *(const float4*)(X + (size_t)r * D + kg * 8);
    const float4 v1 = *(const float4*)(X + (size_t)r * D + kg * 8 + 4);
    const float xs[8] = {v0.x, v0.y, v0.z, v0.w, v1.x, v1.y, v1.z, v1.w};

    float s = 0.f;
    #pragma unroll
    for (int i = 0; i < 8; ++i) s = fmaf(xs[i], xs[i], s);
    #pragma unroll
    for (int off = 1; off < 16; off <<= 1) s += __shfl_xor(s, off);
    if (kg == 0) sqn[r] = s;

    short8 hv, lv;
    #pragma unroll
    for (int i = 0; i < 8; ++i) {
        const float x = xs[i];
        const ushort h = f2bf(x);
        hv[i] = (short)h;
        lv[i] = (short)f2bf(x - bf2f(h));
    }
    const int sw = r & 7;
    ushort* rp = Xh + (size_t)r * 256;
    *(short8*)(rp + ((kg ^ sw) << 3))        = hv;
    *(short8*)(rp + (((16 + kg) ^ sw) << 3)) = lv;

    if (t == 0) *out = 0.0f;
}

__global__ __launch_bounds__(128, 2) void mmcl_mfma_kernel(
    const ushort* __restrict__ Xh, const float* __restrict__ sqn,
    const int* __restrict__ lab,
    float* __restrict__ ppos, float* __restrict__ pneg)
{
    __shared__ ushort lds[2][CT * 256];   // 2 x 16KB double-buffered col tiles
    __shared__ float colp[2][RB];         // per-wave col-side min-pos
    __shared__ float coln[2][RB];         // per-wave col-side max-neg

    const int tid  = threadIdx.x;
    const int w    = tid >> 6;
    const int lane = tid & 63;
    const int lhi  = lane >> 4;
    const int llo  = lane & 15;

    // triangular decode: idx = j*(j+1)/2 + i, i <= j
    const int idx = blockIdx.x;
    int j = (int)((sqrtf(8.0f * (float)idx + 1.0f) - 1.0f) * 0.5f);
    while ((j + 1) * (j + 2) / 2 <= idx) ++j;
    while (j * (j + 1) / 2 > idx) --j;
    const int i = idx - j * (j + 1) / 2;
    const bool isdiag = (i == j);

    const int R  = i * RB + w * 64;   // this wave's 64 rows
    const int C0 = j * RB;            // block's 128 cols

    // init per-wave col buffers (wave-private; no cross-wave race)
    colp[w][lane] = INFINITY;  colp[w][lane + 64] = INFINITY;
    coln[w][lane] = -INFINITY; coln[w][lane + 64] = -INFINITY;

    // A fragments: rows R + m*16 + llo, all K=128 (hi+lo) persistent in registers
    short8 a_hi[4][4], a_lo[4][4];
    #pragma unroll
    for (int m = 0; m < 4; ++m) {
        const int row = R + m * 16 + llo;
        const int sw = row & 7;
        const ushort* rp = Xh + (size_t)row * 256;
        #pragma unroll
        for (int kf = 0; kf < 4; ++kf) {
            const int g = kf * 4 + lhi;
            a_hi[m][kf] = *(const short8*)(rp + ((g ^ sw) << 3));
            a_lo[m][kf] = *(const short8*)(rp + (((16 + g) ^ sw) << 3));
        }
    }

    int labR[4][4];
    #pragma unroll
    for (int m = 0; m < 4; ++m)
        #pragma unroll
        for (int r = 0; r < 4; ++r)
            labR[m][r] = lab[R + m * 16 + lhi * 4 + r];

    float minpos[4][4], maxneg[4][4];
    #pragma unroll
    for (int m = 0; m < 4; ++m)
        #pragma unroll
        for (int r = 0; r < 4; ++r) { minpos[m][r] = INFINITY; maxneg[m][r] = -INFINITY; }

    // stage tile t (16KB contiguous in Xh) into buf; 128 threads x 8 x 16B
    auto stage = [&](int buf, int t) {
        const char* g = (const char*)(Xh + (size_t)(C0 + t * CT) * 256) + tid * 16;
        char* l = (char*)&lds[buf][0] + tid * 16;
        #pragma unroll
        for (int k = 0; k < 8; ++k)
            gload_lds16(g + k * 2048, l + k * 2048);
    };

    stage(0, 0);

    // prefetch col metadata for tile 0
    float sqc_pf[2]; int lc_pf[2];
    #pragma unroll
    for (int n = 0; n < 2; ++n) {
        const int col = C0 + n * 16 + llo;
        sqc_pf[n] = sqn[col];
        lc_pf[n]  = lab[col];
    }

    #pragma unroll 2
    for (int t = 0; t < NCT; ++t) {
        const int cur = t & 1;
        __syncthreads();                 // drains stage(cur); others done reading cur^1
        if (t + 1 < NCT) stage(cur ^ 1, t + 1);

        const int colbase = C0 + t * CT;

        float sqc_u[2]; int lc_u[2];
        #pragma unroll
        for (int n = 0; n < 2; ++n) { sqc_u[n] = sqc_pf[n]; lc_u[n] = lc_pf[n]; }
        if (t + 1 < NCT) {
            #pragma unroll
            for (int n = 0; n < 2; ++n) {
                const int col = colbase + CT + n * 16 + llo;
                sqc_pf[n] = sqn[col];
                lc_pf[n]  = lab[col];
            }
        }

        const bool hasdiag = isdiag && (colbase + CT > R) && (colbase < R + 64);

        #pragma unroll
        for (int n = 0; n < 2; ++n) {
            const int cl = n * 16 + llo;     // (global col)&7 == cl&7
            const int sw = cl & 7;
            const ushort* bp = &lds[cur][cl * 256];
            f32x4 acc[4];
            #pragma unroll
            for (int m = 0; m < 4; ++m) acc[m] = (f32x4){0.f, 0.f, 0.f, 0.f};

            __builtin_amdgcn_s_setprio(1);
            #pragma unroll
            for (int kf = 0; kf < 4; ++kf) {
                const int g = kf * 4 + lhi;
                const short8 b_hi = *(const short8*)(bp + ((g ^ sw) << 3));
                const short8 b_lo = *(const short8*)(bp + (((16 + g) ^ sw) << 3));
                #pragma unroll
                for (int m = 0; m < 4; ++m) {
                    acc[m] = __builtin_amdgcn_mfma_f32_16x16x32_bf16(a_hi[m][kf], b_hi, acc[m], 0, 0, 0);
                    acc[m] = __builtin_amdgcn_mfma_f32_16x16x32_bf16(a_hi[m][kf], b_lo, acc[m], 0, 0, 0);
                    acc[m] = __builtin_amdgcn_mfma_f32_16x16x32_bf16(a_lo[m][kf], b_hi, acc[m], 0, 0, 0);
                }
            }
            __builtin_amdgcn_s_setprio(0);

            const int col   = colbase + cl;
            const float sqc = sqc_u[n];
            const int   lc  = lc_u[n];
            float cvp = INFINITY, cvn = -INFINITY;

            if (hasdiag) {
                #pragma unroll
                for (int m = 0; m < 4; ++m) {
                    const int rowb = R + m * 16 + lhi * 4;
                    #pragma unroll
                    for (int r = 0; r < 4; ++r) {
                        const float v = fmaf(-2.0f, acc[m][r], sqc);
                        const bool same = (labR[m][r] == lc);
                        const bool diag = (rowb + r == col);
                        const float vp = (same && !diag) ? v : INFINITY;
                        const float vn = same ? -INFINITY : v;
                        minpos[m][r] = fminf(minpos[m][r], vp);
                        maxneg[m][r] = fmaxf(maxneg[m][r], vn);
                        cvp = fminf(cvp, vp);
                        cvn = fmaxf(cvn, vn);
                    }
                }
            } else {
                #pragma unroll
                for (int m = 0; m < 4; ++m) {
                    #pragma unroll
                    for (int r = 0; r < 4; ++r) {
                        const float v = fmaf(-2.0f, acc[m][r], sqc);
                        const bool same = (labR[m][r] == lc);
                        const float vp = same ? v : INFINITY;
                        const float vn = same ? -INFINITY : v;
                        minpos[m][r] = fminf(minpos[m][r], vp);
                        maxneg[m][r] = fmaxf(maxneg[m][r], vn);
                        cvp = fminf(cvp, vp);
                        cvn = fmaxf(cvn, vn);
                    }
                }
            }

            // col-side: reduce over lhi (lanes sharing a col), fold into wave's LDS slot
            cvp = fminf(cvp, __shfl_xor(cvp, 16));
            cvp = fminf(cvp, __shfl_xor(cvp, 32));
            cvn = fmaxf(cvn, __shfl_xor(cvn, 16));
            cvn = fmaxf(cvn, __shfl_xor(cvn, 32));
            if (lane < 16) {
                const int c = t * CT + n * 16 + lane;
                colp[w][c] = fminf(colp[w][c], cvp);
                coln[w][c] = fmaxf(coln[w][c], cvn);
            }
        }
    }

    // row-side: reduce over the 16 llo lanes, store slot j for rows of block i
    #pragma unroll
    for (int m = 0; m < 4; ++m)
        #pragma unroll
        for (int r = 0; r < 4; ++r) {
            float mp = minpos[m][r], mn = maxneg[m][r];
            #pragma unroll
            for (int off = 1; off < 16; off <<= 1) {
                mp = fminf(mp, __shfl_xor(mp, off));
                mn = fmaxf(mn, __shfl_xor(mn, off));
            }
            if (llo == 0) {
                const int row = R + m * 16 + lhi * 4 + r;
                ppos[(size_t)row * NSLOT + j] = mp;
                pneg[(size_t)row * NSLOT + j] = mn;
            }
        }

    __syncthreads();   // col slots complete
    // col-side: rows of block j get slot i (skip on diagonal: row-side covered it)
    if (!isdiag) {
        const int c = tid;   // 128 threads == RB cols
        const float cp = fminf(colp[0][c], colp[1][c]);
        const float cn = fmaxf(coln[0][c], coln[1][c]);
        const int row = C0 + c;
        ppos[(size_t)row * NSLOT + i] = cp;
        pneg[(size_t)row * NSLOT + i] = cn;
    }
}

__global__ void mmcl_final_kernel(const float* __restrict__ sqn,
                                  const float* __restrict__ ppos,
                                  const float* __restrict__ pneg,
                                  float* __restrict__ out)
{
    const int row = blockIdx.x * 256 + threadIdx.x;
    const float4* pp = (const float4*)(ppos + (size_t)row * NSLOT);
    const float4* pn = (const float4*)(pneg + (size_t)row * NSLOT);
    float mp = INFINITY, mn = -INFINITY;
    #pragma unroll
    for (int k = 0; k < NSLOT / 4; ++k) {
        const float4 a = pp[k];
        const float4 b = pn[k];
        mp = fminf(mp, fminf(fminf(a.x, a.y), fminf(a.z, a.w)));
        mn = fmaxf(mn, fmaxf(fmaxf(b.x, b.y), fmaxf(b.z, b.w)));
    }
    const float sq  = sqn[row];
    const float pos = isinf(mp) ? INFINITY : sqrtf(fmaxf(sq + mp, 0.f));
    const float neg = (mn == -INFINITY) ? -INFINITY : sqrtf(fmaxf(sq + mn, 0.f));
    const float term = fmaxf(pos - neg + MARGIN, 0.f);

    float s = term;
    #pragma unroll
    for (int off = 32; off; off >>= 1) s += __shfl_down(s, off);
    __shared__ float wsum[4];
    const int wave = threadIdx.x >> 6, lane = threadIdx.x & 63;
    if (lane == 0) wsum[wave] = s;
    __syncthreads();
    if (threadIdx.x == 0)
        atomicAdd(out, (wsum[0] + wsum[1] + wsum[2] + wsum[3]) * (1.0f / B));
}

extern "C" void kernel_launch(void* const* d_in, const int* in_sizes, int n_in,
                              void* d_out, int out_size, void* d_ws, size_t ws_size,
                              hipStream_t stream) {
    (void)in_sizes; (void)n_in; (void)out_size; (void)ws_size;
    const float* X   = (const float*)d_in[0];
    const int*   lab = (const int*)d_in[1];
    float* out = (float*)d_out;

    float*  sqn  = (float*)d_ws;
    float*  ppos = sqn + B;
    float*  pneg = ppos + (size_t)B * NSLOT;
    ushort* Xh   = (ushort*)(pneg + (size_t)B * NSLOT);

    mmcl_prep_kernel<<<(B * 16) / 256, 256, 0, stream>>>(X, Xh, sqn, out);
    mmcl_mfma_kernel<<<NPAIR, 128, 0, stream>>>(Xh, sqn, lab, ppos, pneg);
    mmcl_final_kernel<<<B / 256, 256, 0, stream>>>(sqn, ppos, pneg, out);
}